// Round 5
// baseline (421.593 us; speedup 1.0000x reference)
//
#include <hip/hip_runtime.h>
#include <stdint.h>

typedef unsigned int uint;
typedef unsigned short ushort;

#define NNODES 100000
#define NPAD   100096          // NNODES rounded up to 128
#define NEDGES 1600000
#define RCONST 400
#define CAP    64              // fixed per-node edge capacity
#define ZROW   NNODES          // guaranteed-zero row in xb0/xb1, used for segment padding

// atomic-free binned CSR build
#define NBKT   196             // ceil(NPAD / 512)
#define NBLK_A 512             // binfill blocks
#define EPB    3125            // NEDGES / NBLK_A, exact
#define RUNCAP 64              // per-(block,bucket) slot capacity; mean 16, P(>64)~2e-18

typedef __attribute__((ext_vector_type(8))) short short8;
typedef __attribute__((ext_vector_type(4))) float f32x4;
typedef __attribute__((ext_vector_type(2))) float f32x2;

__device__ __forceinline__ float bflo(uint u){ union{uint i;float f;}c; c.i=u<<16; return c.f; }
__device__ __forceinline__ float bfhi(uint u){ union{uint i;float f;}c; c.i=u&0xFFFF0000u; return c.f; }
__device__ __forceinline__ ushort f2bf(float f){ union{uint i;float ff;}c; c.ff=f; uint u=c.i;
    return (ushort)((u + 0x7FFFu + ((u>>16)&1u))>>16); }
__device__ __forceinline__ uint pack2(float lo, float hi){
    return (uint)f2bf(lo) | ((uint)f2bf(hi)<<16); }

// ---------------- phase A: bin edges by coarse dst bucket, atomic-free ----------------

__global__ __launch_bounds__(256) void binfill_kernel(const int* __restrict__ edges,
                                                      int* __restrict__ runcnt,   // [NBLK_A][NBKT]
                                                      uint* __restrict__ binned) { // [NBKT][NBLK_A][RUNCAP]
    __shared__ int pos[NBKT];
    int blk = blockIdx.x, tid = threadIdx.x;
    for (int i = tid; i < NBKT; i += 256) pos[i] = 0;
    __syncthreads();
    int start = blk * EPB;
    for (int i = tid; i < EPB; i += 256) {
        int e = start + i;
        int src = edges[e * 3];
        int rel = edges[e * 3 + 1];
        int dst = edges[e * 3 + 2];
        int bkt = (rel >= RCONST) + (rel >= 2 * RCONST);
        int b = dst >> 9, off = dst & 511;
        int p = atomicAdd(&pos[b], 1);         // LDS atomic
        if (p < RUNCAP)
            binned[((size_t)b * NBLK_A + blk) * RUNCAP + p] =
                (uint)src | ((uint)bkt << 17) | ((uint)off << 19);
    }
    __syncthreads();
    for (int i = tid; i < NBKT; i += 256)
        runcnt[blk * NBKT + i] = min(pos[i], RUNCAP);
}

// ---------------- phase B: two-pass scatter -> bucket-sorted, pair-padded elist ----------------
// Pass1 counts per (node,bucket) in LDS; per node we compute even-padded segment
// starts, fill the pad slots with ZROW (a zero embedding row), emit cnts
// (true c0,c1,c2, 1/deg) and segp (packed padded lengths). Pass2 places each
// edge at its bucket cursor. All elist writes for 512 nodes come from one block.

__global__ __launch_bounds__(256) void scatter_kernel(const uint* __restrict__ binned,
                                                      const int* __restrict__ runcnt,
                                                      int* __restrict__ elist,    // [NPAD][64]
                                                      uint* __restrict__ segp,    // [NPAD]
                                                      float4* __restrict__ cnts) {// [NPAD]
    __shared__ int cnt3[512][4];   // pass1 counts, then segment LIMITS
    __shared__ int cur[512][4];    // pass2 cursors
    int b = blockIdx.x, tid = threadIdx.x;
    int base = b << 9;
    for (int i = tid; i < 512; i += 256) { cnt3[i][0] = 0; cnt3[i][1] = 0; cnt3[i][2] = 0; }
    __syncthreads();
    // pass 1: count
    #pragma unroll
    for (int rr = 0; rr < 2; ++rr) {
        int r = tid * 2 + rr;
        int n = runcnt[r * NBKT + b];
        const uint* p = binned + ((size_t)b * NBLK_A + r) * RUNCAP;
        for (int i = 0; i < n; ++i) {
            uint e = p[i];
            atomicAdd(&cnt3[e >> 19][(e >> 17) & 3], 1);
        }
    }
    __syncthreads();
    // per-node: starts, dummy padding, metadata
    for (int i = tid; i < 512; i += 256) {
        int node = base + i;
        if (node >= NPAD) continue;
        int c0 = cnt3[i][0], c1 = cnt3[i][1], c2 = cnt3[i][2];
        int n0 = min((c0 + 1) & ~1, 64);
        int n1 = min((c1 + 1) & ~1, 64 - n0);
        int n2 = min((c2 + 1) & ~1, 64 - n0 - n1);
        int s1 = n0, s2 = n0 + n1, tot = n0 + n1 + n2;
        cur[i][0] = 0; cur[i][1] = s1; cur[i][2] = s2;
        int* er = elist + (size_t)node * 64;
        for (int j = min(c0, n0); j < n0; ++j) er[j] = ZROW;
        for (int j = min(c1, n1); j < n1; ++j) er[s1 + j] = ZROW;
        for (int j = min(c2, n2); j < n2; ++j) er[s2 + j] = ZROW;
        cnt3[i][0] = s1; cnt3[i][1] = s2; cnt3[i][2] = tot;   // limits
        segp[node] = (uint)n0 | ((uint)n1 << 8) | ((uint)n2 << 16);
        float4 v;
        v.x = (float)c0; v.y = (float)c1; v.z = (float)c2;
        v.w = 1.0f / fmaxf((float)(c0 + c1 + c2), 1.0f);
        cnts[node] = v;
    }
    __syncthreads();
    // pass 2: place
    #pragma unroll
    for (int rr = 0; rr < 2; ++rr) {
        int r = tid * 2 + rr;
        int n = runcnt[r * NBKT + b];
        const uint* p = binned + ((size_t)b * NBLK_A + r) * RUNCAP;
        for (int i = 0; i < n; ++i) {
            uint e = p[i];
            int off = (int)(e >> 19), bk = (int)((e >> 17) & 3);
            int pos = atomicAdd(&cur[off][bk], 1);
            if (pos < cnt3[off][bk])
                elist[(size_t)(base + off) * 64 + pos] = (int)(e & 0x1FFFFu);
        }
    }
}

// ---------------- conversions ----------------

__global__ __launch_bounds__(256) void convx_kernel(const float* __restrict__ x,
                                                    uint* __restrict__ xb) {
    size_t i = (size_t)blockIdx.x * 256 + threadIdx.x;   // pair index, covers NPAD rows
    if (i < (size_t)NPAD * 64) {
        uint val = 0;
        if (i < (size_t)NNODES * 64) {
            float2 f = *(const float2*)&x[i * 2];
            val = pack2(f.x, f.y);
        }
        xb[i] = val;                 // rows NNODES..NPAD zeroed (ZROW lives here)
    }
}

// Wb[n][k] bf16, k<384: W[k>>7][n][k&127]; k>=384: Ws[n][k-384]
__global__ __launch_bounds__(256) void wconv_kernel(const float* __restrict__ W,
                                                    const float* __restrict__ Ws,
                                                    uint* __restrict__ Wb) {
    int i = blockIdx.x * 256 + threadIdx.x;   // pair index, 128*256
    if (i < 128 * 256) {
        int n = i >> 8, kp = i & 255, k = kp * 2;
        float v0, v1;
        if (k < 384) {
            int r = k >> 7, kk = k & 127;
            const float* p = W + r * 16384 + n * 128 + kk;
            v0 = p[0]; v1 = p[1];
        } else {
            const float* p = Ws + n * 128 + (k - 384);
            v0 = p[0]; v1 = p[1];
        }
        Wb[i] = pack2(v0, v1);
    }
}

// ---------------- gather: one wave per node, 2 edges per step ----------------
// elist is bucket-sorted and pair-padded, so the 3 segment loops are bucket-
// uniform: no one-hot fmafs, no counters. Lanes 0-31 carry edge A, lanes 32-63
// edge B (8 B = 2 bf16-pairs per lane). Accumulate f32x2 (v_pk_add_f32);
// one shfl_xor(32) combine per bucket at the end.

__global__ __launch_bounds__(256) void gather_kernel(
    const uint* __restrict__ xb,       // [NPAD][64] bf16-pairs (+ZROW)
    const uint* __restrict__ segp,     // [NPAD] n0|n1<<8|n2<<16 (padded lengths)
    const int*  __restrict__ elist,    // [NPAD][64] bucket-sorted srcs
    const float4* __restrict__ cnts,   // [NPAD] (c0,c1,c2,inv)
    uint* __restrict__ Ab) {           // [NPAD][192] bf16-pairs
    int tid = threadIdx.x;
    int w = tid >> 6, lane = tid & 63;
    int node = blockIdx.x * 4 + w;     // grid = NNODES/4 exactly
    uint sp = __builtin_amdgcn_readfirstlane(segp[node]);
    float inv = cnts[node].w;
    int ve = elist[(size_t)node * 64 + lane];
    int half = lane >> 5, hl = lane & 31;
    const char* xrow = (const char*)xb + (hl << 3);

    f32x2 a00 = {0.f, 0.f}, a01 = {0.f, 0.f};
    f32x2 a10 = {0.f, 0.f}, a11 = {0.f, 0.f};
    f32x2 a20 = {0.f, 0.f}, a21 = {0.f, 0.f};
    int n0 = (int)(sp & 255), n1 = (int)((sp >> 8) & 255), n2 = (int)((sp >> 16) & 255);
    int eb = 0;

    #define SEG(NB, A0, A1)                                                   \
    for (int j = 0; j < NB; j += 2) {                                         \
        int sA = __builtin_amdgcn_readlane(ve, eb + j);                       \
        int sB = __builtin_amdgcn_readlane(ve, eb + j + 1);                   \
        int ss = half ? sB : sA;                                              \
        uint2 u = *(const uint2*)(xrow + ((size_t)((uint)ss << 8)));          \
        f32x2 f0 = {bflo(u.x), bfhi(u.x)};                                    \
        f32x2 f1 = {bflo(u.y), bfhi(u.y)};                                    \
        A0 += f0; A1 += f1;                                                   \
    }                                                                         \
    eb += NB;

    SEG(n0, a00, a01)
    SEG(n1, a10, a11)
    SEG(n2, a20, a21)
    #undef SEG

    // combine halves, scale by 1/deg
    #define COMB(A) { f32x2 t; t.x = __shfl_xor(A.x, 32); t.y = __shfl_xor(A.y, 32); \
                      A += t; A *= inv; }
    COMB(a00) COMB(a01) COMB(a10) COMB(a11) COMB(a20) COMB(a21)
    #undef COMB

    if (half == 0) {
        size_t ab = (size_t)node * 192 + hl * 2;
        uint2 v0 = { pack2(a00.x, a00.y), pack2(a01.x, a01.y) };
        *(uint2*)&Ab[ab] = v0;
        uint2 v1 = { pack2(a10.x, a10.y), pack2(a11.x, a11.y) };
        *(uint2*)&Ab[ab + 64] = v1;
        uint2 v2 = { pack2(a20.x, a20.y), pack2(a21.x, a21.y) };
        *(uint2*)&Ab[ab + 128] = v2;
    }
}

// ---------------- MFMA GEMM + fused epilogue: LDS-staged, pipelined, swizzled ----------------

template<bool OUT_BF16>
__global__ __launch_bounds__(256, 3) void gemm_kernel(
    const ushort* __restrict__ Ab,     // [NPAD][384]
    const ushort* __restrict__ xb,     // [NPAD][128]
    const ushort* __restrict__ Wb,     // [128][512]
    const float* __restrict__ bia,     // [3][128]
    const float* __restrict__ bs,
    const float* __restrict__ g,
    const float* __restrict__ be,
    const float4* __restrict__ cnts,   // [NPAD] (c0,c1,c2,inv)
    void* __restrict__ out) {
    __shared__ ushort lA[64 * 64];     // 8 KB, swizzled rows of 128 B
    __shared__ ushort lB[128 * 64];    // 16 KB, swizzled rows of 128 B
    __shared__ float sS1[4][64], sS2[4][64];
    __shared__ float sMean[64], sRstd[64];

    int tid = threadIdx.x;
    int w = tid >> 6, lane = tid & 63;
    int wn = w;                        // 4 waves across N
    int quad = lane >> 4, l15 = lane & 15;
    int node0 = blockIdx.x * 64;

    int arow = tid >> 2, aseg = tid & 3;        // A: 64 rows x 8 segs(16B), 2 segs/thread
    int brow = tid >> 1, bseg = (tid & 1) * 4;  // B: 128 rows x 8 segs, 4 segs/thread
    uint swzA = (uint)((arow & 7) << 4);
    uint swzB = (uint)((brow & 7) << 4);
    uint swzR = (uint)((l15 & 7) << 4);         // read-side swizzle (row&7 == l15&7)

    const ushort* gA = Ab + (size_t)node0 * 384;
    const ushort* gX = xb + (size_t)node0 * 128;

    f32x4 accm[4][2], accq[4][2];
    f32x4 zero = {0.f, 0.f, 0.f, 0.f};
    #pragma unroll
    for (int i = 0; i < 4; ++i)
        #pragma unroll
        for (int j = 0; j < 2; ++j) { accm[i][j] = zero; accq[i][j] = zero; }

    uint4 ra0, ra1, rb0, rb1, rb2, rb3;
    auto load_chunk = [&](int t) {
        const ushort* srcA; size_t strA;
        if (t < 6) { srcA = gA + t * 64;       strA = 384; }
        else       { srcA = gX + (t - 6) * 64; strA = 128; }
        const ushort* pa = srcA + (size_t)arow * strA + aseg * 8;
        ra0 = *(const uint4*)(pa);
        ra1 = *(const uint4*)(pa + 32);        // seg+4
        const ushort* pb = Wb + t * 64 + (size_t)brow * 512 + bseg * 8;
        rb0 = *(const uint4*)(pb);
        rb1 = *(const uint4*)(pb + 8);
        rb2 = *(const uint4*)(pb + 16);
        rb3 = *(const uint4*)(pb + 24);
    };
    auto compute = [&](f32x4 (&acc)[4][2]) {
        #pragma unroll
        for (int ks = 0; ks < 2; ++ks) {
            short8 aF[4], bF[2];
            #pragma unroll
            for (int mt = 0; mt < 4; ++mt) {
                int row = mt * 16 + l15;
                aF[mt] = *(const short8*)((const char*)lA + row * 128 +
                                          (((uint)(ks * 64 + quad * 16)) ^ swzR));
            }
            #pragma unroll
            for (int nt = 0; nt < 2; ++nt) {
                int row = wn * 32 + nt * 16 + l15;
                bF[nt] = *(const short8*)((const char*)lB + row * 128 +
                                          (((uint)(ks * 64 + quad * 16)) ^ swzR));
            }
            #pragma unroll
            for (int mt = 0; mt < 4; ++mt)
                #pragma unroll
                for (int nt = 0; nt < 2; ++nt)
                    acc[mt][nt] = __builtin_amdgcn_mfma_f32_16x16x32_bf16(
                        aF[mt], bF[nt], acc[mt][nt], 0, 0, 0);
        }
    };

    load_chunk(0);
    for (int t = 0; t < 8; ++t) {
        if (t) __syncthreads();
        {
            char* bA = (char*)lA + arow * 128;
            *(uint4*)(bA + (((uint)(aseg * 16)) ^ swzA))       = ra0;
            *(uint4*)(bA + (((uint)((aseg + 4) * 16)) ^ swzA)) = ra1;
            char* bB = (char*)lB + brow * 128;
            *(uint4*)(bB + (((uint)((bseg + 0) * 16)) ^ swzB)) = rb0;
            *(uint4*)(bB + (((uint)((bseg + 1) * 16)) ^ swzB)) = rb1;
            *(uint4*)(bB + (((uint)((bseg + 2) * 16)) ^ swzB)) = rb2;
            *(uint4*)(bB + (((uint)((bseg + 3) * 16)) ^ swzB)) = rb3;
        }
        __syncthreads();
        if (t < 7) load_chunk(t + 1);
        if (t < 6) compute(accm); else compute(accq);
    }

    // epilogue: v = relu(accm + bias_msg) + accq + bs, then LN over 128 cols
    int nl0 = wn * 32 + l15;
    float pb0[2], pb1[2], pb2[2], pbs[2], pg[2], pbe[2];
    #pragma unroll
    for (int nt = 0; nt < 2; ++nt) {
        int nl = nl0 + nt * 16;
        pb0[nt] = bia[nl]; pb1[nt] = bia[128 + nl]; pb2[nt] = bia[256 + nl];
        pbs[nt] = bs[nl];  pg[nt] = g[nl];          pbe[nt] = be[nl];
    }
    #pragma unroll
    for (int mt = 0; mt < 4; ++mt) {
        #pragma unroll
        for (int r = 0; r < 4; ++r) {
            int ml = mt * 16 + quad * 4 + r;
            float4 c4 = cnts[node0 + ml];
            float s1 = 0.f, s2 = 0.f;
            #pragma unroll
            for (int nt = 0; nt < 2; ++nt) {
                float bd = (c4.x * pb0[nt] + c4.y * pb1[nt] + c4.z * pb2[nt]) * c4.w;
                float v = fmaxf(accm[mt][nt][r] + bd, 0.f) + accq[mt][nt][r] + pbs[nt];
                accm[mt][nt][r] = v;
                s1 += v; s2 += v * v;
            }
            #pragma unroll
            for (int mask = 1; mask < 16; mask <<= 1) {
                s1 += __shfl_xor(s1, mask);
                s2 += __shfl_xor(s2, mask);
            }
            if (l15 == 0) { sS1[wn][ml] = s1; sS2[wn][ml] = s2; }
        }
    }
    __syncthreads();
    if (tid < 64) {
        float s1 = sS1[0][tid] + sS1[1][tid] + sS1[2][tid] + sS1[3][tid];
        float s2 = sS2[0][tid] + sS2[1][tid] + sS2[2][tid] + sS2[3][tid];
        float mean = s1 * (1.f / 128.f);
        float var = s2 * (1.f / 128.f) - mean * mean;
        sMean[tid] = mean;
        sRstd[tid] = rsqrtf(var + 1e-5f);
    }
    __syncthreads();
    #pragma unroll
    for (int mt = 0; mt < 4; ++mt) {
        #pragma unroll
        for (int r = 0; r < 4; ++r) {
            int ml = mt * 16 + quad * 4 + r;
            int node = node0 + ml;
            float mn = sMean[ml], rs = sRstd[ml];
            #pragma unroll
            for (int nt = 0; nt < 2; ++nt) {
                float v = (accm[mt][nt][r] - mn) * rs * pg[nt] + pbe[nt];
                if (OUT_BF16) {
                    float vh = __shfl_xor(v, 1);
                    if (!(l15 & 1)) {
                        // pad rows (node >= NNODES) MUST be written as zeros:
                        // they back ZROW reads in the next gather.
                        uint val = (node < NNODES) ? pack2(v, vh) : 0u;
                        uint* o = (uint*)out;
                        o[(size_t)node * 64 + wn * 16 + nt * 8 + (l15 >> 1)] = val;
                    }
                } else {
                    if (node < NNODES) {
                        float* o = (float*)out;
                        o[(size_t)node * 128 + nl0 + nt * 16] = v;
                    }
                }
            }
        }
    }
}

// ---------------- launch ----------------

extern "C" void kernel_launch(void* const* d_in, const int* in_sizes, int n_in,
                              void* d_out, int out_size, void* d_ws, size_t ws_size,
                              hipStream_t stream) {
    (void)in_sizes; (void)n_in; (void)out_size; (void)ws_size;

    const int*   edges = (const int*)d_in[0];
    const float* xemb  = (const float*)d_in[1];
    const float* W1  = (const float*)d_in[2];
    const float* b1  = (const float*)d_in[3];
    const float* Ws1 = (const float*)d_in[4];
    const float* bs1 = (const float*)d_in[5];
    const float* g1  = (const float*)d_in[6];
    const float* be1 = (const float*)d_in[7];
    const float* W2  = (const float*)d_in[8];
    const float* b2  = (const float*)d_in[9];
    const float* Ws2 = (const float*)d_in[10];
    const float* bs2 = (const float*)d_in[11];
    const float* g2  = (const float*)d_in[12];
    const float* be2 = (const float*)d_in[13];

    char* ws = (char*)d_ws;
    auto take = [&](size_t bytes) {
        char* p = ws;
        ws += (bytes + 255) & ~(size_t)255;
        return p;
    };
    int*    elist  = (int*)take((size_t)NPAD * CAP * 4);
    uint*   segp   = (uint*)take((size_t)NPAD * 4);
    float4* cnts   = (float4*)take((size_t)NPAD * 16);
    uint*   xb0    = (uint*)take((size_t)NPAD * 128 * 2);
    uint*   xb1    = (uint*)take((size_t)NPAD * 128 * 2);
    uint*   Ab     = (uint*)take((size_t)NPAD * 384 * 2);
    uint*   Wb1    = (uint*)take((size_t)128 * 512 * 2);
    uint*   Wb2    = (uint*)take((size_t)128 * 512 * 2);
    int*    runcnt = (int*)take((size_t)NBLK_A * NBKT * 4);
    uint*   binned = (uint*)take((size_t)NBKT * NBLK_A * RUNCAP * 4);

    binfill_kernel<<<NBLK_A, 256, 0, stream>>>(edges, runcnt, binned);
    scatter_kernel<<<NBKT, 256, 0, stream>>>(binned, runcnt, elist, segp, cnts);

    convx_kernel<<<(NPAD * 64) / 256, 256, 0, stream>>>(xemb, xb0);
    wconv_kernel<<<128, 256, 0, stream>>>(W1, Ws1, Wb1);
    wconv_kernel<<<128, 256, 0, stream>>>(W2, Ws2, Wb2);

    gather_kernel<<<NNODES / 4, 256, 0, stream>>>(xb0, segp, elist, cnts, Ab);
    gemm_kernel<true><<<NPAD / 64, 256, 0, stream>>>(
        (const ushort*)Ab, (const ushort*)xb0, (const ushort*)Wb1,
        b1, bs1, g1, be1, cnts, xb1);

    gather_kernel<<<NNODES / 4, 256, 0, stream>>>(xb1, segp, elist, cnts, Ab);
    gemm_kernel<false><<<NPAD / 64, 256, 0, stream>>>(
        (const ushort*)Ab, (const ushort*)xb1, (const ushort*)Wb2,
        b2, bs2, g2, be2, cnts, d_out);
}